// Round 1
// baseline (47093.192 us; speedup 1.0000x reference)
//
#include <hip/hip_runtime.h>
#include <hip/hip_bf16.h>

// MomentumDecoder: 2-layer LSTM (B=512, H=512), 256 autoregressive steps.
// Design (round 0): 32 WGs x 1024 threads; each WG owns 16 batch rows for the
// whole 256-step recurrence. MFMA f32_16x16x32_f16, weights streamed from L2/L3
// as f16 (pre-converted into d_ws), h-state in XOR-swizzled LDS, c-state in
// registers laid out to match the MFMA C/D fragment mapping.

#define B_ 512
#define H_ 512
#define T_ 256

typedef _Float16 half8_t __attribute__((ext_vector_type(8)));
typedef _Float16 half4_t __attribute__((ext_vector_type(4)));
typedef float floatx4 __attribute__((ext_vector_type(4)));

// ---------------- prep: convert the 3 big weight matrices f32 -> f16 ----------------
// layout in ws: [W_hh0 | W_ih1 | W_hh1], each 4H*H = 1048576 f16 elements.
__global__ void prep_weights(const float* __restrict__ whh0,
                             const float* __restrict__ wih1,
                             const float* __restrict__ whh1,
                             _Float16* __restrict__ w16) {
    const int QM = (4 * H_ * H_) / 4;  // float4 count per matrix = 262144
    int i = blockIdx.x * blockDim.x + threadIdx.x;  // 0 .. 3*QM-1
    if (i >= 3 * QM) return;
    const float* src;
    int base;
    if (i < QM)          { src = whh0; base = 0; }
    else if (i < 2 * QM) { src = wih1; base = QM; }
    else                 { src = whh1; base = 2 * QM; }
    float4 v = ((const float4*)src)[i - base];
    half4_t h;
    h[0] = (_Float16)v.x; h[1] = (_Float16)v.y;
    h[2] = (_Float16)v.z; h[3] = (_Float16)v.w;
    ((half4_t*)w16)[i] = h;
}

__device__ __forceinline__ float sigm_(float x) { return 1.0f / (1.0f + __expf(-x)); }
__device__ __forceinline__ float tanh_(float x) { return 1.0f - 2.0f / (1.0f + __expf(2.0f * x)); }

// XOR swizzle: byte offset within a [16][512] f16 row-major tile.
// Spreads the 16 same-column rows of an A-fragment ds_read_b128 across banks
// (2 lanes/bank residual aliasing = free per m136).
__device__ __forceinline__ int swz(int row, int col_elems) {
    return (row * 1024 + col_elems * 2) ^ ((row & 7) << 4);
}

// ---------------- main persistent-per-batch-group kernel ----------------
__launch_bounds__(1024)
__global__ void lstm_decode(const float* __restrict__ h_in,
                            const float* __restrict__ c_in,
                            const float* __restrict__ wih0,   // (4H,1) f32
                            const float* __restrict__ bih0,
                            const float* __restrict__ bhh0,
                            const float* __restrict__ bih1,
                            const float* __restrict__ bhh1,
                            const float* __restrict__ fcw,    // (1,H) f32
                            const float* __restrict__ fcb,    // (1,)
                            const _Float16* __restrict__ w16, // [Whh0|Wih1|Whh1] f16
                            float* __restrict__ out) {        // (B, T) f32
    __shared__ unsigned short h0b[16 * 512];  // f16 bits, swizzled
    __shared__ unsigned short h1b[16 * 512];
    __shared__ float xbuf[16];

    const int tid  = (int)threadIdx.x;
    const int lane = tid & 63;
    const int wv   = tid >> 6;          // wave 0..15, owns h-cols [32*wv, 32*wv+32)
    const int brow = (int)blockIdx.x * 16;

    char* h0c = (char*)h0b;
    char* h1c = (char*)h1b;

    // ---- init h state (f32 -> f16, swizzled) ----
    for (int idx = tid; idx < 16 * 512; idx += 1024) {
        int row = idx >> 9, col = idx & 511;
        int off = swz(row, col);
        *(_Float16*)(h0c + off) = (_Float16)h_in[(size_t)(brow + row) * H_ + col];
        *(_Float16*)(h1c + off) = (_Float16)h_in[(size_t)B_ * H_ + (size_t)(brow + row) * H_ + col];
    }
    if (tid < 16) xbuf[tid] = 0.0f;  // start token x = 0

    // ---- c state in registers, matching MFMA C/D layout:
    // col = lane&15 (+tile), row = (lane>>4)*4 + reg  [m89-verified]
    const int rbase = (lane >> 4) * 4;
    const int cl    = lane & 15;
    float c0[8], c1[8];
#pragma unroll
    for (int s = 0; s < 2; ++s)
#pragma unroll
        for (int r = 0; r < 4; ++r) {
            int row = rbase + r, col = wv * 32 + s * 16 + cl;
            c0[s * 4 + r] = c_in[(size_t)(brow + row) * H_ + col];
            c1[s * 4 + r] = c_in[(size_t)B_ * H_ + (size_t)(brow + row) * H_ + col];
        }

    const _Float16* W0 = w16;                    // W_hh0
    const _Float16* W1 = w16 + 4 * H_ * H_;      // W_ih1
    const _Float16* W2 = w16 + 2 * 4 * H_ * H_;  // W_hh1

    // per-thread gate-row indices and hoisted per-row constants
    size_t noff[4][2];
    float bias0v[4][2], bias1v[4][2], wxv[4][2];
#pragma unroll
    for (int q = 0; q < 4; ++q)
#pragma unroll
        for (int s = 0; s < 2; ++s) {
            int n = q * H_ + wv * 32 + s * 16 + cl;
            noff[q][s]   = (size_t)n * H_;
            bias0v[q][s] = bih0[n] + bhh0[n];
            bias1v[q][s] = bih1[n] + bhh1[n];
            wxv[q][s]    = wih0[n];
        }
    const float fcb0 = fcb[0];

    const int am   = cl;               // A-fragment row
    const int kgrp = (lane >> 4) * 8;  // k sub-offset within a 32-wide K step

    __syncthreads();

    for (int t = 0; t < T_; ++t) {
        floatx4 acc[4][2];

        // ======== layer 0: gates = x*Wih0 + h0*Whh0^T + bias ========
        {
            float xr[4];
#pragma unroll
            for (int r = 0; r < 4; ++r) xr[r] = xbuf[rbase + r];
#pragma unroll
            for (int q = 0; q < 4; ++q)
#pragma unroll
                for (int s = 0; s < 2; ++s) {
                    float b = bias0v[q][s], wx = wxv[q][s];
                    floatx4 a;
#pragma unroll
                    for (int r = 0; r < 4; ++r) a[r] = __builtin_fmaf(xr[r], wx, b);
                    acc[q][s] = a;
                }
        }
#pragma unroll 2
        for (int ks = 0; ks < 16; ++ks) {
            half8_t av = *(const half8_t*)(h0c + swz(am, ks * 32 + kgrp));
#pragma unroll
            for (int q = 0; q < 4; ++q)
#pragma unroll
                for (int s = 0; s < 2; ++s) {
                    half8_t bv = *(const half8_t*)(W0 + noff[q][s] + ks * 32 + kgrp);
                    acc[q][s] = __builtin_amdgcn_mfma_f32_16x16x32_f16(av, bv, acc[q][s], 0, 0, 0);
                }
        }
        __syncthreads();  // all A-reads of h0 done
        // h0/c0 update
#pragma unroll
        for (int s = 0; s < 2; ++s)
#pragma unroll
            for (int r = 0; r < 4; ++r) {
                float iv = acc[0][s][r], fv = acc[1][s][r];
                float gv = acc[2][s][r], ov = acc[3][s][r];
                float cc = sigm_(fv) * c0[s * 4 + r] + sigm_(iv) * tanh_(gv);
                c0[s * 4 + r] = cc;
                float hv = sigm_(ov) * tanh_(cc);
                *(_Float16*)(h0c + swz(rbase + r, wv * 32 + s * 16 + cl)) = (_Float16)hv;
            }
        __syncthreads();  // h0_new visible

        // ======== layer 1: gates = h0_new*Wih1^T + h1*Whh1^T + bias ========
#pragma unroll
        for (int q = 0; q < 4; ++q)
#pragma unroll
            for (int s = 0; s < 2; ++s) {
                float b = bias1v[q][s];
                floatx4 a;
#pragma unroll
                for (int r = 0; r < 4; ++r) a[r] = b;
                acc[q][s] = a;
            }
#pragma unroll 2
        for (int ks = 0; ks < 16; ++ks) {
            half8_t av = *(const half8_t*)(h0c + swz(am, ks * 32 + kgrp));
#pragma unroll
            for (int q = 0; q < 4; ++q)
#pragma unroll
                for (int s = 0; s < 2; ++s) {
                    half8_t bv = *(const half8_t*)(W1 + noff[q][s] + ks * 32 + kgrp);
                    acc[q][s] = __builtin_amdgcn_mfma_f32_16x16x32_f16(av, bv, acc[q][s], 0, 0, 0);
                }
        }
#pragma unroll 2
        for (int ks = 0; ks < 16; ++ks) {
            half8_t av = *(const half8_t*)(h1c + swz(am, ks * 32 + kgrp));
#pragma unroll
            for (int q = 0; q < 4; ++q)
#pragma unroll
                for (int s = 0; s < 2; ++s) {
                    half8_t bv = *(const half8_t*)(W2 + noff[q][s] + ks * 32 + kgrp);
                    acc[q][s] = __builtin_amdgcn_mfma_f32_16x16x32_f16(av, bv, acc[q][s], 0, 0, 0);
                }
        }
        __syncthreads();  // all A-reads of h1 done
        // h1/c1 update
#pragma unroll
        for (int s = 0; s < 2; ++s)
#pragma unroll
            for (int r = 0; r < 4; ++r) {
                float iv = acc[0][s][r], fv = acc[1][s][r];
                float gv = acc[2][s][r], ov = acc[3][s][r];
                float cc = sigm_(fv) * c1[s * 4 + r] + sigm_(iv) * tanh_(gv);
                c1[s * 4 + r] = cc;
                float hv = sigm_(ov) * tanh_(cc);
                *(_Float16*)(h1c + swz(rbase + r, wv * 32 + s * 16 + cl)) = (_Float16)hv;
            }
        __syncthreads();  // h1_new visible

        // ======== FC head: pred[row] = h1_new[row,:] . fcw + fcb ========
        {
            int row  = wv;           // 16 waves, one row each
            int koff = lane * 8;     // 64 lanes x 8 cols
            half8_t hv = *(const half8_t*)(h1c + swz(row, koff));
            const float4* fw = (const float4*)(fcw + koff);
            float4 f0 = fw[0], f1 = fw[1];
            float sum = (float)hv[0] * f0.x + (float)hv[1] * f0.y +
                        (float)hv[2] * f0.z + (float)hv[3] * f0.w +
                        (float)hv[4] * f1.x + (float)hv[5] * f1.y +
                        (float)hv[6] * f1.z + (float)hv[7] * f1.w;
#pragma unroll
            for (int o = 32; o; o >>= 1) sum += __shfl_xor(sum, o);
            if (lane == 0) {
                float p = sum + fcb0;
                out[(size_t)(brow + row) * T_ + t] = p;
                xbuf[row] = p;
            }
        }
        __syncthreads();  // xbuf ready for next step
    }
}

extern "C" void kernel_launch(void* const* d_in, const int* in_sizes, int n_in,
                              void* d_out, int out_size, void* d_ws, size_t ws_size,
                              hipStream_t stream) {
    const float* h_in  = (const float*)d_in[0];
    const float* c_in  = (const float*)d_in[1];
    const float* wih0  = (const float*)d_in[2];
    const float* whh0  = (const float*)d_in[3];
    const float* bih0  = (const float*)d_in[4];
    const float* bhh0  = (const float*)d_in[5];
    const float* wih1  = (const float*)d_in[6];
    const float* whh1  = (const float*)d_in[7];
    const float* bih1  = (const float*)d_in[8];
    const float* bhh1  = (const float*)d_in[9];
    const float* fcw   = (const float*)d_in[10];
    const float* fcb   = (const float*)d_in[11];
    float* out = (float*)d_out;

    _Float16* w16 = (_Float16*)d_ws;  // needs 3 * 4H*H * 2B = 6 MiB

    // convert the 3 big weight matrices to f16 (deterministic, every call)
    {
        const int n4 = 3 * (4 * H_ * H_) / 4;  // 786432 float4s
        int threads = 256;
        int blocks = (n4 + threads - 1) / threads;
        prep_weights<<<blocks, threads, 0, stream>>>(whh0, wih1, whh1, w16);
    }

    lstm_decode<<<B_ / 16, 1024, 0, stream>>>(h_in, c_in, wih0, bih0, bhh0,
                                              bih1, bhh1, fcw, fcb, w16, out);
}

// Round 3
// 10447.682 us; speedup vs baseline: 4.5075x; 4.5075x over previous
//
#include <hip/hip_runtime.h>
#include <hip/hip_bf16.h>

// MomentumDecoder: 2-layer LSTM (B=512,H=512), 256 autoregressive steps.
// Round 2 (fixed compile): weights-stationary persistent kernel. 256 WGs x 512
// thr (1 per CU), WG = (batch-tile bt: 64 rows, col-tile ct: 16 hidden cols).
// All weight fragments live in VGPRs (96/lane). Per step: phase A (G0 full,
// G1 partial), grid barrier, phase B (G1 finish + FC reduce via atomicAdd into
// out), grid barrier. h-state ping-pongs in d_ws as f16; x feedback from out.

#define B_ 512
#define H_ 512
#define T_ 256
#define NWG 256
#define NTHR 512

typedef _Float16 half8_t __attribute__((ext_vector_type(8)));
typedef _Float16 half4_t __attribute__((ext_vector_type(4)));
typedef _Float16 half2_t __attribute__((ext_vector_type(2)));
typedef float floatx4 __attribute__((ext_vector_type(4)));

// ---- d_ws layout ----
#define W16_BYTES (3u * 4u * H_ * H_ * 2u)   // 6 MiB: [W_hh0 | W_ih1 | W_hh1] f16
#define HBUF_ELEMS (B_ * H_)                 // one h-state buffer (f16)
#define HBUF_BYTES (HBUF_ELEMS * 2u)         // 512 KiB
#define H0_OFF  ((size_t)W16_BYTES)
#define H1_OFF  (H0_OFF + 2 * HBUF_BYTES)
#define BAR_OFF (H1_OFF + 2 * HBUF_BYTES)    // barrier counters (zeroed each call)

__device__ __forceinline__ float sigm_(float x) { return 1.0f / (1.0f + __expf(-x)); }
__device__ __forceinline__ float tanh_(float x) { return 1.0f - 2.0f / (1.0f + __expf(2.0f * x)); }

// ---------------- prep: f32 -> f16 weight conversion ----------------
__global__ void prep_weights(const float* __restrict__ whh0,
                             const float* __restrict__ wih1,
                             const float* __restrict__ whh1,
                             _Float16* __restrict__ w16) {
    const int QM = (4 * H_ * H_) / 4;  // 262144 float4 per matrix
    int i = blockIdx.x * blockDim.x + threadIdx.x;
    if (i >= 3 * QM) return;
    const float* src; int base;
    if (i < QM)          { src = whh0; base = 0; }
    else if (i < 2 * QM) { src = wih1; base = QM; }
    else                 { src = whh1; base = 2 * QM; }
    float4 v = ((const float4*)src)[i - base];
    half4_t h;
    h[0] = (_Float16)v.x; h[1] = (_Float16)v.y; h[2] = (_Float16)v.z; h[3] = (_Float16)v.w;
    ((half4_t*)w16)[i] = h;
}

// ---------------- prep: h-state f32 -> f16 ----------------
__global__ void prep_state(const float* __restrict__ h_in,
                           _Float16* __restrict__ H0, _Float16* __restrict__ H1) {
    int i = blockIdx.x * blockDim.x + threadIdx.x;  // 4 elems each
    float4 a = ((const float4*)h_in)[i];
    float4 b = ((const float4*)h_in)[(B_ * H_) / 4 + i];
    half4_t ha, hb;
    ha[0] = (_Float16)a.x; ha[1] = (_Float16)a.y; ha[2] = (_Float16)a.z; ha[3] = (_Float16)a.w;
    hb[0] = (_Float16)b.x; hb[1] = (_Float16)b.y; hb[2] = (_Float16)b.z; hb[3] = (_Float16)b.w;
    ((half4_t*)H0)[i] = ha;
    ((half4_t*)H1)[i] = hb;
}

// ---------------- helpers ----------------
#define GLL16(gp, lp) __builtin_amdgcn_global_load_lds( \
    (const __attribute__((address_space(1))) unsigned int*)(gp), \
    (__attribute__((address_space(3))) unsigned int*)(lp), 16, 0, 0)

// Stage 8 rows (this wave's share) of a 64x512 f16 row-major tile into LDS.
// Source address is pre-XOR-swizzled per 16B granule so the linear LDS write
// leaves data where the swizzled ds_read (^((row&7)<<4)) expects it.
__device__ __forceinline__ void stage_rows(const char* gsrc, char* lbuf, int wv, int lane) {
#pragma unroll
    for (int i = 0; i < 8; ++i) {
        int row = wv * 8 + i;
        const char* gp = gsrc + row * 1024 + (((lane ^ (row & 7)) & 63) << 4);
        GLL16(gp, lbuf + row * 1024);
    }
}

// Two-level grid barrier: 8 group counters (by blockIdx&7) -> root counter.
// Agent-scope atomics + __threadfence on both sides for cross-XCD coherence.
__device__ __forceinline__ void grid_barrier(int* bar) {
    __syncthreads();
    if (threadIdx.x == 0) {
        __threadfence();  // release: make this WG's global writes agent-visible
        int* grp   = bar + 16 + (blockIdx.x & 7) * 16;
        int* rootc = bar;
        int* gen   = bar + 4;
        int gcur = __hip_atomic_load(gen, __ATOMIC_RELAXED, __HIP_MEMORY_SCOPE_AGENT);
        if (__hip_atomic_fetch_add(grp, 1, __ATOMIC_ACQ_REL, __HIP_MEMORY_SCOPE_AGENT) == 31) {
            __hip_atomic_store(grp, 0, __ATOMIC_RELAXED, __HIP_MEMORY_SCOPE_AGENT);
            if (__hip_atomic_fetch_add(rootc, 1, __ATOMIC_ACQ_REL, __HIP_MEMORY_SCOPE_AGENT) == 7) {
                __hip_atomic_store(rootc, 0, __ATOMIC_RELAXED, __HIP_MEMORY_SCOPE_AGENT);
                __hip_atomic_store(gen, gcur + 1, __ATOMIC_RELEASE, __HIP_MEMORY_SCOPE_AGENT);
            } else {
                while (__hip_atomic_load(gen, __ATOMIC_RELAXED, __HIP_MEMORY_SCOPE_AGENT) == gcur)
                    __builtin_amdgcn_s_sleep(2);
            }
        } else {
            while (__hip_atomic_load(gen, __ATOMIC_RELAXED, __HIP_MEMORY_SCOPE_AGENT) == gcur)
                __builtin_amdgcn_s_sleep(2);
        }
        __threadfence();  // acquire: discard stale cached lines before re-reading
    }
    __syncthreads();
}

// MFMA pass: acc[mt] += A(LDS tile, swizzled) x wf[ksg], 8 K-steps of 32.
#define PASS(bufc, wf, acc) do {                                              \
    _Pragma("unroll")                                                         \
    for (int ksg = 0; ksg < 8; ++ksg) {                                       \
        _Pragma("unroll")                                                     \
        for (int mt = 0; mt < 4; ++mt) {                                      \
            int a_ = (abase + mt * 16384 + ksg * 64) ^ axor;                  \
            half8_t av_ = *(const half8_t*)((bufc) + a_);                     \
            acc[mt] = __builtin_amdgcn_mfma_f32_16x16x32_f16(av_, (wf)[ksg],  \
                                                             acc[mt], 0, 0, 0); \
        }                                                                     \
    }                                                                         \
} while (0)

// ---------------- main persistent kernel ----------------
__launch_bounds__(NTHR, 2)
__global__ void lstm_decode(
    const float* __restrict__ c_in,
    const float* __restrict__ wih0, const float* __restrict__ bih0,
    const float* __restrict__ bhh0,
    const float* __restrict__ bih1, const float* __restrict__ bhh1,
    const float* __restrict__ fcw, const float* __restrict__ fcb,
    const _Float16* __restrict__ w16,
    _Float16* __restrict__ Hs0,   // 2 ping-pong buffers
    _Float16* __restrict__ Hs1,
    int* __restrict__ bar,
    float* __restrict__ outp)     // (B, T), zeroed; accumulated via atomicAdd
{
    __shared__ __align__(16) char bufA[65536];  // 64x512 f16 A-tile
    __shared__ __align__(16) char bufB[65536];
    __shared__ float gbuf[4][64][16];           // gate reduce + FC products

    const int tid  = (int)threadIdx.x;
    const int lane = tid & 63;
    const int wv   = tid >> 6;    // 0..7
    const int g    = wv & 3;      // gate (i,f,g,o)
    const int kh   = wv >> 2;     // K half (0: k<256, 1: k>=256)
    const int cl   = lane & 15;
    const int kg   = lane >> 4;   // 0..3
    const int bt   = (int)blockIdx.x & 7;   // batch tile (also XCD group)
    const int ct   = (int)blockIdx.x >> 3;  // col tile 0..31

    // ---- persistent weight fragments in VGPRs ----
    const int n = g * H_ + ct * 16 + cl;    // gate-row index
    half8_t wf0[8], wf1[8], wf2[8];
    {
        const _Float16* r0 = w16 + (size_t)n * H_ + kh * 256 + kg * 8;
        const _Float16* r1 = r0 + 4 * H_ * H_;
        const _Float16* r2 = r0 + 8 * H_ * H_;
#pragma unroll
        for (int ksg = 0; ksg < 8; ++ksg) {
            wf0[ksg] = *(const half8_t*)(r0 + ksg * 32);
            wf1[ksg] = *(const half8_t*)(r1 + ksg * 32);
            wf2[ksg] = *(const half8_t*)(r2 + ksg * 32);
        }
    }
    const float b0   = bih0[n] + bhh0[n];
    const float b1   = bih1[n] + bhh1[n];
    const float wx   = wih0[n];
    const float fcb0 = fcb[0];

    // ---- elementwise domain: thread owns (erow, ecol..ecol+1) of 64x16 ----
    const int erow = tid >> 3;
    const int ecol = (tid & 7) * 2;
    float c0a, c0b, c1a, c1b;
    {
        size_t base0 = (size_t)(bt * 64 + erow) * H_ + ct * 16 + ecol;
        c0a = c_in[base0];
        c0b = c_in[base0 + 1];
        c1a = c_in[(size_t)B_ * H_ + base0];
        c1b = c_in[(size_t)B_ * H_ + base0 + 1];
    }
    const float2 fcv = *(const float2*)(fcw + ct * 16 + ecol);

    // ---- A-fragment ds_read base (row = mt*16+cl, k = kh*256+ksg*32+kg*8) ----
    const int abase = cl * 1024 + kh * 512 + kg * 16;
    const int axor  = (cl & 7) << 4;

    floatx4 accG0[4], accG1[4];

    for (int t = 0; t < T_; ++t) {
        const char* h0r = (const char*)Hs0 + (size_t)(t & 1) * HBUF_BYTES + (size_t)bt * 64 * 1024;
        const char* h1r = (const char*)Hs1 + (size_t)(t & 1) * HBUF_BYTES + (size_t)bt * 64 * 1024;
        _Float16* h0w = Hs0 + (size_t)((t + 1) & 1) * HBUF_ELEMS;
        _Float16* h1w = Hs1 + (size_t)((t + 1) & 1) * HBUF_ELEMS;

        // ======== phase A ========
        // x feedback (kh==0 waves only): per-row scalar from out[:, t-1]
        float xv[4][4];
        if (kh == 0) {
            if (t > 0) {
#pragma unroll
                for (int mt = 0; mt < 4; ++mt)
#pragma unroll
                    for (int r = 0; r < 4; ++r)
                        xv[mt][r] = outp[(size_t)(bt * 64 + mt * 16 + kg * 4 + r) * T_ + (t - 1)];
            } else {
#pragma unroll
                for (int mt = 0; mt < 4; ++mt)
#pragma unroll
                    for (int r = 0; r < 4; ++r) xv[mt][r] = 0.f;
            }
        }
        stage_rows(h0r, bufA, wv, lane);   // 8 gll each
        stage_rows(h1r, bufB, wv, lane);   // 8 gll each
#pragma unroll
        for (int mt = 0; mt < 4; ++mt) {
            if (kh == 0) {
#pragma unroll
                for (int r = 0; r < 4; ++r) {
                    accG0[mt][r] = __builtin_fmaf(xv[mt][r], wx, b0);
                    accG1[mt][r] = b1;
                }
            } else {
#pragma unroll
                for (int r = 0; r < 4; ++r) { accG0[mt][r] = 0.f; accG1[mt][r] = 0.f; }
            }
        }
        // bufA ready once every wave has <=8 outstanding VMEM (its bufB loads)
        asm volatile("s_waitcnt vmcnt(8) lgkmcnt(0)\n\ts_barrier" ::: "memory");
        PASS(bufA, wf0, accG0);            // h0 x W_hh0^T
        asm volatile("s_waitcnt vmcnt(0) lgkmcnt(0)\n\ts_barrier" ::: "memory");
        PASS(bufB, wf2, accG1);            // h1 x W_hh1^T (partial for layer 1)

        // reduce G0 across kh halves via LDS
        if (kh == 0) {
#pragma unroll
            for (int mt = 0; mt < 4; ++mt)
#pragma unroll
                for (int r = 0; r < 4; ++r)
                    gbuf[g][mt * 16 + kg * 4 + r][cl] = accG0[mt][r];
        }
        __syncthreads();
        if (kh == 1) {
#pragma unroll
            for (int mt = 0; mt < 4; ++mt)
#pragma unroll
                for (int r = 0; r < 4; ++r)
                    gbuf[g][mt * 16 + kg * 4 + r][cl] += accG0[mt][r];
        }
        __syncthreads();
        // layer-0 elementwise: c0,h0_new ; store h0_new (f16) to global
        {
            float2 iv = *(const float2*)&gbuf[0][erow][ecol];
            float2 fv = *(const float2*)&gbuf[1][erow][ecol];
            float2 gv = *(const float2*)&gbuf[2][erow][ecol];
            float2 ov = *(const float2*)&gbuf[3][erow][ecol];
            float ca = sigm_(fv.x) * c0a + sigm_(iv.x) * tanh_(gv.x);
            float cb = sigm_(fv.y) * c0b + sigm_(iv.y) * tanh_(gv.y);
            c0a = ca; c0b = cb;
            half2_t hh;
            hh[0] = (_Float16)(sigm_(ov.x) * tanh_(ca));
            hh[1] = (_Float16)(sigm_(ov.y) * tanh_(cb));
            *(half2_t*)(h0w + (size_t)(bt * 64 + erow) * H_ + ct * 16 + ecol) = hh;
        }
        grid_barrier(bar);

        // ======== phase B ========
        stage_rows((const char*)h0w + (size_t)bt * 64 * 1024, bufA, wv, lane);
        asm volatile("s_waitcnt vmcnt(0) lgkmcnt(0)\n\ts_barrier" ::: "memory");
        PASS(bufA, wf1, accG1);            // h0_new x W_ih1^T

        if (kh == 0) {
#pragma unroll
            for (int mt = 0; mt < 4; ++mt)
#pragma unroll
                for (int r = 0; r < 4; ++r)
                    gbuf[g][mt * 16 + kg * 4 + r][cl] = accG1[mt][r];
        }
        __syncthreads();
        if (kh == 1) {
#pragma unroll
            for (int mt = 0; mt < 4; ++mt)
#pragma unroll
                for (int r = 0; r < 4; ++r)
                    gbuf[g][mt * 16 + kg * 4 + r][cl] += accG1[mt][r];
        }
        __syncthreads();
        // layer-1 elementwise + FC partial products
        {
            float2 iv = *(const float2*)&gbuf[0][erow][ecol];
            float2 fv = *(const float2*)&gbuf[1][erow][ecol];
            float2 gv = *(const float2*)&gbuf[2][erow][ecol];
            float2 ov = *(const float2*)&gbuf[3][erow][ecol];
            float ca = sigm_(fv.x) * c1a + sigm_(iv.x) * tanh_(gv.x);
            float cb = sigm_(fv.y) * c1b + sigm_(iv.y) * tanh_(gv.y);
            c1a = ca; c1b = cb;
            float ha = sigm_(ov.x) * tanh_(ca);
            float hb = sigm_(ov.y) * tanh_(cb);
            half2_t hh; hh[0] = (_Float16)ha; hh[1] = (_Float16)hb;
            *(half2_t*)(h1w + (size_t)(bt * 64 + erow) * H_ + ct * 16 + ecol) = hh;
            // FC products into gbuf[0] (each thread overwrites only slots it read)
            float2 pr; pr.x = ha * fcv.x; pr.y = hb * fcv.y;
            *(float2*)&gbuf[0][erow][ecol] = pr;
        }
        __syncthreads();
        if (tid < 64) {
            float s = (ct == 0) ? fcb0 : 0.f;
#pragma unroll
            for (int c2 = 0; c2 < 16; ++c2) s += gbuf[0][tid][c2];
            atomicAdd(&outp[(size_t)(bt * 64 + tid) * T_ + t], s);
        }
        grid_barrier(bar);
    }
}

extern "C" void kernel_launch(void* const* d_in, const int* in_sizes, int n_in,
                              void* d_out, int out_size, void* d_ws, size_t ws_size,
                              hipStream_t stream) {
    const float* h_in = (const float*)d_in[0];
    const float* c_in = (const float*)d_in[1];
    const float* wih0 = (const float*)d_in[2];
    const float* whh0 = (const float*)d_in[3];
    const float* bih0 = (const float*)d_in[4];
    const float* bhh0 = (const float*)d_in[5];
    const float* wih1 = (const float*)d_in[6];
    const float* whh1 = (const float*)d_in[7];
    const float* bih1 = (const float*)d_in[8];
    const float* bhh1 = (const float*)d_in[9];
    const float* fcw  = (const float*)d_in[10];
    const float* fcb  = (const float*)d_in[11];
    float* out = (float*)d_out;

    char* ws = (char*)d_ws;
    _Float16* w16 = (_Float16*)ws;
    _Float16* Hs0 = (_Float16*)(ws + H0_OFF);
    _Float16* Hs1 = (_Float16*)(ws + H1_OFF);
    int* bar      = (int*)(ws + BAR_OFF);

    // out accumulates atomically and doubles as x-feedback: zero it each call.
    (void)hipMemsetAsync(out, 0, (size_t)B_ * T_ * sizeof(float), stream);
    // barrier counters must start at 0 (d_ws gets poisoned between calls).
    (void)hipMemsetAsync(bar, 0, 1024, stream);

    {
        const int n4 = 3 * (4 * H_ * H_) / 4;
        prep_weights<<<(n4 + 255) / 256, 256, 0, stream>>>(whh0, wih1, whh1, w16);
    }
    prep_state<<<(B_ * H_ / 4) / 256, 256, 0, stream>>>(h_in, Hs0, Hs1);

    lstm_decode<<<NWG, NTHR, 0, stream>>>(c_in, wih0, bih0, bhh0, bih1, bhh1,
                                          fcw, fcb, w16, Hs0, Hs1, bar, out);
}

// Round 4
// 3139.184 us; speedup vs baseline: 15.0017x; 3.3282x over previous
//
#include <hip/hip_runtime.h>
#include <hip/hip_bf16.h>

// MomentumDecoder: 2-layer LSTM (B=512,H=512), 256 autoregressive steps.
// Round 4: fence-free flag barriers + explicit L3-coherent data path.
// 256 WGs x 512 thr (1/CU), WG=(bt:64 batch rows, ct:16 hidden cols).
// Weights (3 matrices) live in VGPRs. Per step:
//   phase A: [GLL h1->bufA | MFMA h0(bufB)xWhh0] -> MFMA h1xWhh1 partial ->
//            gate0 exchange -> EW0 -> h0_new stores -> flag barrier A
//   phase B: GLL h0_new->bufB -> MFMA xWih1 -> gate1 exchange -> EW1 ->
//            FC shfl partial -> flag barrier B
// x feedback: every WG reduces the 32 FC partials next step (no atomics).

#define B_ 512
#define H_ 512
#define T_ 256
#define NWG 256
#define NTHR 512

typedef _Float16 half8_t __attribute__((ext_vector_type(8)));
typedef _Float16 half4_t __attribute__((ext_vector_type(4)));
typedef _Float16 half2_t __attribute__((ext_vector_type(2)));
typedef float floatx4 __attribute__((ext_vector_type(4)));

// ---- d_ws layout ----
#define W16_BYTES  (3u * 4u * H_ * H_ * 2u)     // 6 MiB f16 [W_hh0|W_ih1|W_hh1]
#define HBUF_ELEMS (B_ * H_)
#define HBUF_BYTES (HBUF_ELEMS * 2u)            // 512 KiB
#define H0_OFF   ((size_t)W16_BYTES)
#define H1_OFF   (H0_OFF + 2 * HBUF_BYTES)
#define BAR_OFF  (H1_OFF + 2 * HBUF_BYTES)      // 8 groups x 32 ints = 1 KiB
#define PART_OFF (BAR_OFF + 1024)               // 8 groups x 64 rows x 32 ct f32 = 64 KiB

__device__ __forceinline__ float sigm_(float x) { return 1.0f / (1.0f + __expf(-x)); }
__device__ __forceinline__ float tanh_(float x) { return 1.0f - 2.0f / (1.0f + __expf(2.0f * x)); }

// ---------------- prep kernels ----------------
__global__ void prep_weights(const float* __restrict__ whh0,
                             const float* __restrict__ wih1,
                             const float* __restrict__ whh1,
                             _Float16* __restrict__ w16) {
    const int QM = (4 * H_ * H_) / 4;
    int i = blockIdx.x * blockDim.x + threadIdx.x;
    if (i >= 3 * QM) return;
    const float* src; int base;
    if (i < QM)          { src = whh0; base = 0; }
    else if (i < 2 * QM) { src = wih1; base = QM; }
    else                 { src = whh1; base = 2 * QM; }
    float4 v = ((const float4*)src)[i - base];
    half4_t h;
    h[0] = (_Float16)v.x; h[1] = (_Float16)v.y; h[2] = (_Float16)v.z; h[3] = (_Float16)v.w;
    ((half4_t*)w16)[i] = h;
}

__global__ void prep_state(const float* __restrict__ h_in,
                           _Float16* __restrict__ H0, _Float16* __restrict__ H1) {
    int i = blockIdx.x * blockDim.x + threadIdx.x;
    float4 a = ((const float4*)h_in)[i];
    float4 b = ((const float4*)h_in)[(B_ * H_) / 4 + i];
    half4_t ha, hb;
    ha[0] = (_Float16)a.x; ha[1] = (_Float16)a.y; ha[2] = (_Float16)a.z; ha[3] = (_Float16)a.w;
    hb[0] = (_Float16)b.x; hb[1] = (_Float16)b.y; hb[2] = (_Float16)b.z; hb[3] = (_Float16)b.w;
    ((half4_t*)H0)[i] = ha;
    ((half4_t*)H1)[i] = hb;
}

// ---------------- helpers ----------------
// global->LDS 16B with SC0|SC1 (bypass L1/L2 -> read L3-fresh data): aux=0x11
#define GLL16(gp, lp) __builtin_amdgcn_global_load_lds( \
    (const __attribute__((address_space(1))) unsigned int*)(gp), \
    (__attribute__((address_space(3))) unsigned int*)(lp), 16, 0, 0x11)

// Stage this wave's 8 rows of a 64x512 f16 tile; source pre-XOR-swizzled so
// linear LDS writes match the ^((row&7)<<4) ds_read swizzle.
__device__ __forceinline__ void stage_rows(const char* gsrc, char* lbuf, int wv, int lane) {
#pragma unroll
    for (int i = 0; i < 8; ++i) {
        int row = wv * 8 + i;
        const char* gp = gsrc + row * 1024 + (((lane ^ (row & 7)) & 63) << 4);
        GLL16(gp, lbuf + row * 1024);
    }
}

#define PASS(bufc, wf, acc) do {                                              \
    _Pragma("unroll")                                                         \
    for (int ksg = 0; ksg < 8; ++ksg) {                                       \
        _Pragma("unroll")                                                     \
        for (int mt = 0; mt < 4; ++mt) {                                      \
            int a_ = (abase + mt * 16384 + ksg * 64) ^ axor;                  \
            half8_t av_ = *(const half8_t*)((bufc) + a_);                     \
            acc[mt] = __builtin_amdgcn_mfma_f32_16x16x32_f16(av_, (wf)[ksg],  \
                                                             acc[mt], 0, 0, 0); \
        }                                                                     \
    }                                                                         \
} while (0)

// ---------------- main persistent kernel ----------------
__launch_bounds__(NTHR)
__global__ void lstm_decode(
    const float* __restrict__ c_in,
    const float* __restrict__ wih0, const float* __restrict__ bih0,
    const float* __restrict__ bhh0,
    const float* __restrict__ bih1, const float* __restrict__ bhh1,
    const float* __restrict__ fcw, const float* __restrict__ fcb,
    const _Float16* __restrict__ w16,
    _Float16* __restrict__ Hs0, _Float16* __restrict__ Hs1,
    int* __restrict__ bar, float* __restrict__ part,
    float* __restrict__ outp)
{
    __shared__ __align__(16) char bufA[65536];   // h1 tile (phase A)
    __shared__ __align__(16) char bufB[65536];   // h0 tile (persists A->B->next A)
    __shared__ float gbuf[4][64][20];            // gate exchange, padded (<=2-way)
    __shared__ float xrow[64];

    const int tid  = (int)threadIdx.x;
    const int lane = tid & 63;
    const int wv   = tid >> 6;    // 0..7
    const int g    = wv & 3;      // gate (i,f,g,o)
    const int kh   = wv >> 2;     // K half
    const int cl   = lane & 15;
    const int kg   = lane >> 4;   // 0..3
    const int bt   = (int)blockIdx.x & 7;
    const int ct   = (int)blockIdx.x >> 3;

    // ---- persistent weight fragments ----
    const int n = g * H_ + ct * 16 + cl;
    half8_t wf0[8], wf1[8], wf2[8];
    {
        const _Float16* r0 = w16 + (size_t)n * H_ + kh * 256 + kg * 8;
        const _Float16* r1 = r0 + 4 * H_ * H_;
        const _Float16* r2 = r0 + 8 * H_ * H_;
#pragma unroll
        for (int ksg = 0; ksg < 8; ++ksg) {
            wf0[ksg] = *(const half8_t*)(r0 + ksg * 32);
            wf1[ksg] = *(const half8_t*)(r1 + ksg * 32);
            wf2[ksg] = *(const half8_t*)(r2 + ksg * 32);
        }
    }
    const float b0   = bih0[n] + bhh0[n];
    const float b1   = bih1[n] + bhh1[n];
    const float wx   = wih0[n];
    const float fcb0 = fcb[0];

    // ---- elementwise domain ----
    const int erow = tid >> 3;
    const int ecol = (tid & 7) * 2;
    float c0a, c0b, c1a, c1b;
    {
        size_t base0 = (size_t)(bt * 64 + erow) * H_ + ct * 16 + ecol;
        c0a = c_in[base0];                     c0b = c_in[base0 + 1];
        c1a = c_in[(size_t)B_ * H_ + base0];   c1b = c_in[(size_t)B_ * H_ + base0 + 1];
    }
    const float2 fcv = *(const float2*)(fcw + ct * 16 + ecol);

    const int abase = cl * 1024 + kh * 512 + kg * 16;
    const int axor  = (cl & 7) << 4;

    int* flagg = bar + bt * 32;              // this group's 32 counters
    float* partg = part + bt * 2048;         // [64 rows][32 ct]
    int ep = 0;

    if (tid < 64) xrow[tid] = 0.f;
    // prologue: stage initial h0 into bufB
    stage_rows((const char*)Hs0 + (size_t)bt * 64 * 1024, bufB, wv, lane);

    floatx4 accG0[4], accG1[4];

    for (int t = 0; t < T_; ++t) {
        const char* h1r = (const char*)Hs1 + (size_t)(t & 1) * HBUF_BYTES + (size_t)bt * 64 * 1024;
        _Float16* h0w = Hs0 + (size_t)((t + 1) & 1) * HBUF_ELEMS;
        _Float16* h1w = Hs1 + (size_t)((t + 1) & 1) * HBUF_ELEMS;

        // ======== phase A ========
        stage_rows(h1r, bufA, wv, lane);          // h1 -> bufA (overlaps pass G0)

        if (t > 0) {                              // x(t-1) = fcb + sum of 32 partials
            const float* pb = partg + (tid >> 3) * 32 + (tid & 7) * 4;
            float s0 = __hip_atomic_load(pb + 0, __ATOMIC_RELAXED, __HIP_MEMORY_SCOPE_AGENT);
            float s1 = __hip_atomic_load(pb + 1, __ATOMIC_RELAXED, __HIP_MEMORY_SCOPE_AGENT);
            float s2 = __hip_atomic_load(pb + 2, __ATOMIC_RELAXED, __HIP_MEMORY_SCOPE_AGENT);
            float s3 = __hip_atomic_load(pb + 3, __ATOMIC_RELAXED, __HIP_MEMORY_SCOPE_AGENT);
            float xs = (s0 + s1) + (s2 + s3);
            xs += __shfl_xor(xs, 1);
            xs += __shfl_xor(xs, 2);
            xs += __shfl_xor(xs, 4);
            xs += fcb0;
            if ((tid & 7) == 0) {
                xrow[tid >> 3] = xs;
                if (ct == 0) outp[(size_t)(bt * 64 + (tid >> 3)) * T_ + (t - 1)] = xs;
            }
        }
        __syncthreads();                          // xrow visible

        // acc init (kh==0 carries bias + x*wx; kh==1 zero)
#pragma unroll
        for (int mt = 0; mt < 4; ++mt) {
            if (kh == 0) {
#pragma unroll
                for (int r = 0; r < 4; ++r) {
                    accG0[mt][r] = __builtin_fmaf(xrow[mt * 16 + kg * 4 + r], wx, b0);
                    accG1[mt][r] = b1;
                }
            } else {
#pragma unroll
                for (int r = 0; r < 4; ++r) { accG0[mt][r] = 0.f; accG1[mt][r] = 0.f; }
            }
        }
        if (t == 0)  // prologue bufB stage must be complete across all waves
            asm volatile("s_waitcnt vmcnt(0) lgkmcnt(0)\n\ts_barrier" ::: "memory");

        PASS(bufB, wf0, accG0);                   // h0 x W_hh0^T
        asm volatile("s_waitcnt vmcnt(0) lgkmcnt(0)\n\ts_barrier" ::: "memory");
        PASS(bufA, wf2, accG1);                   // h1 x W_hh1^T (partial)

        // gate0 exchange across kh halves
        if (kh == 0) {
#pragma unroll
            for (int mt = 0; mt < 4; ++mt)
#pragma unroll
                for (int r = 0; r < 4; ++r)
                    gbuf[g][mt * 16 + kg * 4 + r][cl] = accG0[mt][r];
        }
        __syncthreads();
        if (kh == 1) {
#pragma unroll
            for (int mt = 0; mt < 4; ++mt)
#pragma unroll
                for (int r = 0; r < 4; ++r)
                    gbuf[g][mt * 16 + kg * 4 + r][cl] += accG0[mt][r];
        }
        __syncthreads();
        // EW layer 0
        {
            float2 iv = *(const float2*)&gbuf[0][erow][ecol];
            float2 fv = *(const float2*)&gbuf[1][erow][ecol];
            float2 gv = *(const float2*)&gbuf[2][erow][ecol];
            float2 ov = *(const float2*)&gbuf[3][erow][ecol];
            float ca = sigm_(fv.x) * c0a + sigm_(iv.x) * tanh_(gv.x);
            float cb = sigm_(fv.y) * c0b + sigm_(iv.y) * tanh_(gv.y);
            c0a = ca; c0b = cb;
            half2_t hh;
            hh[0] = (_Float16)(sigm_(ov.x) * tanh_(ca));
            hh[1] = (_Float16)(sigm_(ov.y) * tanh_(cb));
            unsigned int u = __builtin_bit_cast(unsigned int, hh);
            unsigned int* dst = (unsigned int*)(h0w + (size_t)(bt * 64 + erow) * H_ + ct * 16 + ecol);
            __hip_atomic_store(dst, u, __ATOMIC_RELAXED, __HIP_MEMORY_SCOPE_AGENT);
        }
        // ---- barrier A (flag-based, fence-free) ----
        ++ep;
        __syncthreads();                          // drains each wave's vmcnt
        if (wv == 0) {
            if (lane == 0)
                __hip_atomic_store(&flagg[ct], ep, __ATOMIC_RELAXED, __HIP_MEMORY_SCOPE_AGENT);
            for (;;) {
                int v = __hip_atomic_load(&flagg[lane & 31], __ATOMIC_RELAXED, __HIP_MEMORY_SCOPE_AGENT);
                if (__all(v >= ep)) break;
                __builtin_amdgcn_s_sleep(1);
            }
        }
        __syncthreads();

        // ======== phase B ========
        stage_rows((const char*)h0w + (size_t)bt * 64 * 1024, bufB, wv, lane);
        asm volatile("s_waitcnt vmcnt(0) lgkmcnt(0)\n\ts_barrier" ::: "memory");
        PASS(bufB, wf1, accG1);                   // h0_new x W_ih1^T

        if (kh == 0) {
#pragma unroll
            for (int mt = 0; mt < 4; ++mt)
#pragma unroll
                for (int r = 0; r < 4; ++r)
                    gbuf[g][mt * 16 + kg * 4 + r][cl] = accG1[mt][r];
        }
        __syncthreads();
        if (kh == 1) {
#pragma unroll
            for (int mt = 0; mt < 4; ++mt)
#pragma unroll
                for (int r = 0; r < 4; ++r)
                    gbuf[g][mt * 16 + kg * 4 + r][cl] += accG1[mt][r];
        }
        __syncthreads();
        // EW layer 1 + FC partial
        {
            float2 iv = *(const float2*)&gbuf[0][erow][ecol];
            float2 fv = *(const float2*)&gbuf[1][erow][ecol];
            float2 gv = *(const float2*)&gbuf[2][erow][ecol];
            float2 ov = *(const float2*)&gbuf[3][erow][ecol];
            float ca = sigm_(fv.x) * c1a + sigm_(iv.x) * tanh_(gv.x);
            float cb = sigm_(fv.y) * c1b + sigm_(iv.y) * tanh_(gv.y);
            c1a = ca; c1b = cb;
            float ha = sigm_(ov.x) * tanh_(ca);
            float hb = sigm_(ov.y) * tanh_(cb);
            half2_t hh; hh[0] = (_Float16)ha; hh[1] = (_Float16)hb;
            unsigned int u = __builtin_bit_cast(unsigned int, hh);
            unsigned int* dst = (unsigned int*)(h1w + (size_t)(bt * 64 + erow) * H_ + ct * 16 + ecol);
            __hip_atomic_store(dst, u, __ATOMIC_RELAXED, __HIP_MEMORY_SCOPE_AGENT);
            // FC: sum this WG's 16 cols for row erow (8 lanes x 2 cols)
            float ps = __builtin_fmaf(ha, fcv.x, hb * fcv.y);
            ps += __shfl_xor(ps, 1);
            ps += __shfl_xor(ps, 2);
            ps += __shfl_xor(ps, 4);
            if ((tid & 7) == 0)
                __hip_atomic_store(&partg[erow * 32 + ct], ps, __ATOMIC_RELAXED, __HIP_MEMORY_SCOPE_AGENT);
        }
        // ---- barrier B ----
        ++ep;
        __syncthreads();
        if (wv == 0) {
            if (lane == 0)
                __hip_atomic_store(&flagg[ct], ep, __ATOMIC_RELAXED, __HIP_MEMORY_SCOPE_AGENT);
            for (;;) {
                int v = __hip_atomic_load(&flagg[lane & 31], __ATOMIC_RELAXED, __HIP_MEMORY_SCOPE_AGENT);
                if (__all(v >= ep)) break;
                __builtin_amdgcn_s_sleep(1);
            }
        }
        __syncthreads();
    }

    // epilogue: final x -> outp column T_-1
    if (ct == 0) {
        const float* pb = partg + (tid >> 3) * 32 + (tid & 7) * 4;
        float s0 = __hip_atomic_load(pb + 0, __ATOMIC_RELAXED, __HIP_MEMORY_SCOPE_AGENT);
        float s1 = __hip_atomic_load(pb + 1, __ATOMIC_RELAXED, __HIP_MEMORY_SCOPE_AGENT);
        float s2 = __hip_atomic_load(pb + 2, __ATOMIC_RELAXED, __HIP_MEMORY_SCOPE_AGENT);
        float s3 = __hip_atomic_load(pb + 3, __ATOMIC_RELAXED, __HIP_MEMORY_SCOPE_AGENT);
        float xs = (s0 + s1) + (s2 + s3);
        xs += __shfl_xor(xs, 1);
        xs += __shfl_xor(xs, 2);
        xs += __shfl_xor(xs, 4);
        xs += fcb0;
        if ((tid & 7) == 0)
            outp[(size_t)(bt * 64 + (tid >> 3)) * T_ + (T_ - 1)] = xs;
    }
}

extern "C" void kernel_launch(void* const* d_in, const int* in_sizes, int n_in,
                              void* d_out, int out_size, void* d_ws, size_t ws_size,
                              hipStream_t stream) {
    const float* h_in = (const float*)d_in[0];
    const float* c_in = (const float*)d_in[1];
    const float* wih0 = (const float*)d_in[2];
    const float* whh0 = (const float*)d_in[3];
    const float* bih0 = (const float*)d_in[4];
    const float* bhh0 = (const float*)d_in[5];
    const float* wih1 = (const float*)d_in[6];
    const float* whh1 = (const float*)d_in[7];
    const float* bih1 = (const float*)d_in[8];
    const float* bhh1 = (const float*)d_in[9];
    const float* fcw  = (const float*)d_in[10];
    const float* fcb  = (const float*)d_in[11];
    float* out = (float*)d_out;

    char* ws = (char*)d_ws;
    _Float16* w16 = (_Float16*)ws;
    _Float16* Hs0 = (_Float16*)(ws + H0_OFF);
    _Float16* Hs1 = (_Float16*)(ws + H1_OFF);
    int* bar      = (int*)(ws + BAR_OFF);
    float* part   = (float*)(ws + PART_OFF);

    // flag counters must start at 0 (ws poisoned between calls)
    (void)hipMemsetAsync(bar, 0, 1024, stream);

    {
        const int n4 = 3 * (4 * H_ * H_) / 4;
        prep_weights<<<(n4 + 255) / 256, 256, 0, stream>>>(whh0, wih1, whh1, w16);
    }
    prep_state<<<(B_ * H_ / 4) / 256, 256, 0, stream>>>(h_in, Hs0, Hs1);

    lstm_decode<<<NWG, NTHR, 0, stream>>>(c_in, wih0, bih0, bhh0, bih1, bhh1,
                                          fcw, fcb, w16, Hs0, Hs1, bar, part, out);
}